// Round 9
// baseline (58.188 us; speedup 1.0000x reference)
//
#include <hip/hip_runtime.h>
#include <math.h>

// SurrogateCanny fused kernel, round 8 (= round 7 resubmitted; infra failure).
// R6 (53.3us) is VALU-bound with ~196 VALU inst/pixel vs ~110 in source.
// Hypothesis: compiler if-converts the rare atanf/div fallback into the hot
// path. This round: (1) fallback forced out-of-line via __noinline__ call,
// (2) sqrt eliminated from hot path (squared compares + margin fallback),
// (3) factored-exact sobel. All transformations bit-exact w.r.t. round 0.

constexpr int W = 1024, H = 1024;
constexpr int TX = 128, TY = 16;         // output tile per block (256 threads)
constexpr int IH = TY + 4, IW2 = 136;    // img tile: rows by0-2..by0+17, cols bx0-4..bx0+131
constexpr int GH = TY + 2, GSTR = 132;   // s2 plane: rows r=-1..16 (idx r+1), cols p=c+1

__device__ __forceinline__ void sobel_pair(float a00, float a01, float a02,
                                           float a10, float a12,
                                           float a20, float a21, float a22,
                                           float& gxv, float& gyv) {
  // Factored form, bit-identical to the reference row-major accumulation:
  // pow-2 scaling and negation commute with round-to-nearest; each product
  // by +-0.5/+-1 is exact, so rounding points are unchanged.
  float t1 = 0.5f * (a02 - a00);     // == fl(-0.5*a00 + 0.5*a02)
  float t2 = t1 - a10;
  float t3 = t2 + a12;
  float t4 = t3 - 0.5f * a20;
  gxv = t4 + 0.5f * a22;
  float p1 = 0.5f * a00 + a01;       // == -fl(-0.5*a00 - a01)
  float p2 = p1 + 0.5f * a02;        // == -s2
  float u3 = 0.5f * a20 - p2;        // == fl(s2 + 0.5*a20)
  float u4 = u3 + a21;
  gyv = u4 + 0.5f * a22;
}

// Exact reference path (rare). noinline so it cannot be if-converted into
// the hot path. Replicates round 0's passing pipeline exactly.
__device__ __attribute__((noinline)) float slow_decide(
    float gxv, float gyv, float sc, float thr,
    float s0a, float s0b, float s1a, float s1b,
    float s2a, float s2b, float s3a, float s3b) {
#pragma clang fp contract(off)
  const float C = (float)(360.0 / M_PI);
  float r  = gyv / gxv;
  float t  = atanf(r);
  float u  = t * C;
  float v2 = u + 180.0f;
  float w  = v2 / 45.0f;
  int   kk = (int)rintf(w);
  int   d  = kk & 3;
  float sn1 = (d == 0) ? s0a : (d == 1) ? s1a : (d == 2) ? s2a : s3a;
  float sn2 = (d == 0) ? s0b : (d == 1) ? s1b : (d == 2) ? s2b : s3b;
  float gmc = sqrtf(sc), n1 = sqrtf(sn1), n2 = sqrtf(sn2);
  bool keep = (gmc - n1 > 0.0f) && (gmc - n2 > 0.0f) && (gmc - thr > 0.0f);
  return keep ? 1.0f : 0.0f;
}

// Hot path: orientation by comparator network; NMS/threshold on SQUARED
// magnitudes with conservative margin. Any uncertainty -> slow_decide.
// Args: center s, then (n1,n2) squared-neighbor pairs for d=0..3.
__device__ __forceinline__ float decide(float gxv, float gyv, float sc,
                                        float s0a, float s0b, float s1a, float s1b,
                                        float s2a, float s2b, float s3a, float s3b,
                                        float thr, float thr2) {
#pragma clang fp contract(off)
  const float T1 = 0.19891236737965801f, D1 = 5.0e-5f;
  const float T2 = 0.66817863791929898f, D2 = 7.0e-5f;
  const float T3 = 1.49660576266548901f, D3 = 1.5e-4f;
  const float T4 = 5.02733949212584810f, D4 = 1.2e-3f;

  const float av = fabsf(gyv), bv = fabsf(gxv);
  const float c1 = fmaf(-T1, bv, av);
  const float c2 = fmaf(-T2, bv, av);
  const float c3 = fmaf(-T3, bv, av);
  const float c4 = fmaf(-T4, bv, av);
  const bool nearb = (fabsf(c1) < D1 * bv) || (fabsf(c2) < D2 * bv) ||
                     (fabsf(c3) < D3 * bv) || (fabsf(c4) < D4 * bv);

  const unsigned sgn = (__float_as_uint(gyv) ^ __float_as_uint(gxv)) >> 31;
  int d;
  if (c1 < 0.0f)      d = 0;
  else if (c2 < 0.0f) d = sgn ? 3 : 1;
  else if (c3 < 0.0f) d = 2;
  else if (c4 < 0.0f) d = sgn ? 1 : 3;
  else                d = 0;

  const float sn1 = (d == 0) ? s0a : (d == 1) ? s1a : (d == 2) ? s2a : s3a;
  const float sn2 = (d == 0) ? s0b : (d == 1) ? s1b : (d == 2) ? s2b : s3b;

  // raw: sign-exact reject side (sqrt monotone). sure: strict with margin
  // 1-2e-6 (covers the ~2.4e-7 sqrt-tie band + the multiply's own rounding).
  const float scl = sc * 0.999998f;
  const bool raw  = (sc  > sn1) && (sc  > sn2) && (sc  > thr2);
  const bool sure = (scl > sn1) && (scl > sn2) && (scl > thr2);

  if (__builtin_expect(nearb || (raw != sure), 0))
    return slow_decide(gxv, gyv, sc, thr, s0a, s0b, s1a, s1b, s2a, s2b, s3a, s3b);
  return sure ? 1.0f : 0.0f;
}

__global__ __launch_bounds__(256)
void canny_kernel(const float* __restrict__ img, const float* __restrict__ thrp,
                  float* __restrict__ out) {
#pragma clang fp contract(off)
  __shared__ __align__(16) float s_img[IH][IW2];
  __shared__ __align__(16) float s_sq[GH][GSTR];   // squared grad magnitude

  const int b   = blockIdx.z;
  const int bx0 = blockIdx.x * TX;
  const int by0 = blockIdx.y * TY;
  const float* im = img + (size_t)b * (W * H);
  float* ob       = out + (size_t)b * (W * H);
  const int tid = threadIdx.x;
  const bool edge = (bx0 == 0) || (bx0 + TX == W) || (by0 == 0) || (by0 + TY == H);

  // ---- Stage img tile: rows by0-2..by0+17, cols bx0-4..bx0+131, zero outside ----
  // 20 rows x 34 float4 = 680 units; row stride 136 floats = 34 float4 -> LDS
  // destination address is u*16 bytes (fully linear).
  if (!edge) {
    const float* base = im + (size_t)(by0 - 2) * W + (bx0 - 4);
    {
      int u = tid;
      int row = u / 34, col = u - row * 34;
      *reinterpret_cast<float4*>(&s_img[0][0] + u * 4) =
          *reinterpret_cast<const float4*>(base + row * W + col * 4);
    }
    {
      int u = tid + 256;
      int row = u / 34, col = u - row * 34;
      *reinterpret_cast<float4*>(&s_img[0][0] + u * 4) =
          *reinterpret_cast<const float4*>(base + row * W + col * 4);
    }
    {
      int u = tid + 512;
      if (u < 680) {
        int row = u / 34, col = u - row * 34;
        *reinterpret_cast<float4*>(&s_img[0][0] + u * 4) =
            *reinterpret_cast<const float4*>(base + row * W + col * 4);
      }
    }
  } else {
    for (int i = tid; i < IH * IW2; i += 256) {
      int r = i / IW2, cx = i - r * IW2;
      int gy = by0 - 2 + r, gx = bx0 - 4 + cx;
      float v = 0.0f;
      if ((unsigned)gy < 1024u && (unsigned)gx < 1024u) v = im[gy * W + gx];
      s_img[r][cx] = v;
    }
  }
  __syncthreads();

  const int c  = tid & 127;           // owned column (image col bx0+c)
  const int tz = tid >> 7;            // strip: pixel rows 8*tz .. 8*tz+7

  // ---- s2 phase: 10 rows per thread, rows r = 8*tz-1 .. 8*tz+8 ----
  // Window tile rows for step Q: tr0+Q .. tr0+Q+2 with tr0 = 8*tz; col c uses
  // s_img cols c+3..c+5. Rows 7,8 duplicated across strips: identical bits.
  float gq0, gq1, gq2, gq3, gq4, gq5, gq6, gq7, gq8, gq9;
  float gx0, gx1, gx2, gx3, gx4, gx5, gx6, gx7;
  float gy0, gy1, gy2, gy3, gy4, gy5, gy6, gy7;
  {
    const int tr0 = 8 * tz;
    const int rowbase = by0 + tr0 - 1;     // image row at Q=0
    float x0 = s_img[tr0][c + 3],     x1 = s_img[tr0][c + 4],     x2 = s_img[tr0][c + 5];
    float y0 = s_img[tr0 + 1][c + 3], y1 = s_img[tr0 + 1][c + 4], y2 = s_img[tr0 + 1][c + 5];

#define GM_STEP(Q, GQ, SAVE)                                                   \
    {                                                                          \
      float z0 = s_img[tr0 + Q + 2][c + 3];                                    \
      float z1 = s_img[tr0 + Q + 2][c + 4];                                    \
      float z2 = s_img[tr0 + Q + 2][c + 5];                                    \
      float gxv, gyv;                                                          \
      sobel_pair(x0, x1, x2, y0, y2, z0, z1, z2, gxv, gyv);                    \
      float sq = gxv * gxv + gyv * gyv;                                        \
      if (edge) { if ((unsigned)(rowbase + Q) >= 1024u) sq = 0.0f; }           \
      s_sq[tr0 + Q][c + 1] = sq;                                               \
      GQ = sq;                                                                 \
      SAVE;                                                                    \
      x0 = y0; x1 = y1; x2 = y2;                                               \
      y0 = z0; y1 = z1; y2 = z2;                                               \
    }

    GM_STEP(0, gq0, (void)0)
    GM_STEP(1, gq1, ((gx0 = gxv), (gy0 = gyv)))
    GM_STEP(2, gq2, ((gx1 = gxv), (gy1 = gyv)))
    GM_STEP(3, gq3, ((gx2 = gxv), (gy2 = gyv)))
    GM_STEP(4, gq4, ((gx3 = gxv), (gy3 = gyv)))
    GM_STEP(5, gq5, ((gx4 = gxv), (gy4 = gyv)))
    GM_STEP(6, gq6, ((gx5 = gxv), (gy5 = gyv)))
    GM_STEP(7, gq7, ((gx6 = gxv), (gy6 = gyv)))
    GM_STEP(8, gq8, ((gx7 = gxv), (gy7 = gyv)))
    GM_STEP(9, gq9, (void)0)
#undef GM_STEP
  }

  // halo cols c=-1 (p=0) and c=128 (p=129): rows r=-1..16 -> 36 elements
  if (tid < 36) {
    int rr = tid >> 1;                     // 0..17, gm row r = rr-1
    int r  = rr - 1;
    int cc = (tid & 1) ? 128 : -1;
    float gxv, gyv;
    sobel_pair(s_img[rr][cc + 3],     s_img[rr][cc + 4],     s_img[rr][cc + 5],
               s_img[rr + 1][cc + 3],                        s_img[rr + 1][cc + 5],
               s_img[rr + 2][cc + 3], s_img[rr + 2][cc + 4], s_img[rr + 2][cc + 5],
               gxv, gyv);
    float sq = gxv * gxv + gyv * gyv;
    if (!((unsigned)(by0 + r) < 1024u && (unsigned)(bx0 + cc) < 1024u)) sq = 0.0f;
    s_sq[rr][cc + 1] = sq;
  }
  __syncthreads();

  // ---- pixel phase: 8-pixel column per thread ----
  // L_k / R_k = s2 of cols c-1 / c+1 at gm row 8*tz-1+k  (s_sq idx 8*tz+k).
  {
    const float thr  = *thrp;
    const float thr2 = thr * thr;
    const int gb = 8 * tz;
    const float L0 = s_sq[gb + 0][c], R0 = s_sq[gb + 0][c + 2];
    const float L1 = s_sq[gb + 1][c], R1 = s_sq[gb + 1][c + 2];
    const float L2 = s_sq[gb + 2][c], R2 = s_sq[gb + 2][c + 2];
    const float L3 = s_sq[gb + 3][c], R3 = s_sq[gb + 3][c + 2];
    const float L4 = s_sq[gb + 4][c], R4 = s_sq[gb + 4][c + 2];
    const float L5 = s_sq[gb + 5][c], R5 = s_sq[gb + 5][c + 2];
    const float L6 = s_sq[gb + 6][c], R6 = s_sq[gb + 6][c + 2];
    const float L7 = s_sq[gb + 7][c], R7 = s_sq[gb + 7][c + 2];
    const float L8 = s_sq[gb + 8][c], R8 = s_sq[gb + 8][c + 2];
    const float L9 = s_sq[gb + 9][c], R9 = s_sq[gb + 9][c + 2];

    float* orow = ob + (size_t)(by0 + gb) * W + bx0 + c;

    // pixel k: sc=gq[k+1]; d0:(R[k+1],L[k+1]) d1:(R[k],L[k+2])
    //          d2:(gq[k],gq[k+2]) d3:(L[k],R[k+2])
    orow[0 * W] = decide(gx0, gy0, gq1, R1, L1, R0, L2, gq0, gq2, L0, R2, thr, thr2);
    orow[1 * W] = decide(gx1, gy1, gq2, R2, L2, R1, L3, gq1, gq3, L1, R3, thr, thr2);
    orow[2 * W] = decide(gx2, gy2, gq3, R3, L3, R2, L4, gq2, gq4, L2, R4, thr, thr2);
    orow[3 * W] = decide(gx3, gy3, gq4, R4, L4, R3, L5, gq3, gq5, L3, R5, thr, thr2);
    orow[4 * W] = decide(gx4, gy4, gq5, R5, L5, R4, L6, gq4, gq6, L4, R6, thr, thr2);
    orow[5 * W] = decide(gx5, gy5, gq6, R6, L6, R5, L7, gq5, gq7, L5, R7, thr, thr2);
    orow[6 * W] = decide(gx6, gy6, gq7, R7, L7, R6, L8, gq6, gq8, L6, R8, thr, thr2);
    orow[7 * W] = decide(gx7, gy7, gq8, R8, L8, R7, L9, gq7, gq9, L7, R9, thr, thr2);
  }
}

extern "C" void kernel_launch(void* const* d_in, const int* in_sizes, int n_in,
                              void* d_out, int out_size, void* d_ws, size_t ws_size,
                              hipStream_t stream) {
  const float* img = (const float*)d_in[0];
  const float* thr = (const float*)d_in[4];
  float* out = (float*)d_out;
  const int batch = in_sizes[0] / (W * H);

  dim3 grid(W / TX, H / TY, batch);
  canny_kernel<<<grid, dim3(256), 0, stream>>>(img, thr, out);
}

// Round 10
// 55.189 us; speedup vs baseline: 1.0543x; 1.0543x over previous
//
#include <hip/hip_runtime.h>
#include <math.h>

// SurrogateCanny fused kernel, round 9.
// R8's noinline-call fallback regressed (occupancy 54->41%, call ABI cost)
// even though VALU work fell. This round: R6's inline structure + R8's
// verified math cuts (squared compares, factored sobel), with the exact
// atanf path INLINE behind a wave-uniform __any() branch (s_cbranch skip,
// no call, no if-conversion). All math bit-exact w.r.t. round 0.

constexpr int W = 1024, H = 1024;
constexpr int TX = 128, TY = 16;         // output tile per block (256 threads)
constexpr int IH = TY + 4, IW2 = 136;    // img tile: rows by0-2..by0+17, cols bx0-4..bx0+131
constexpr int GH = TY + 2, GSTR = 132;   // s2 plane: rows r=-1..16 (idx r+1), cols p=c+1

__device__ __forceinline__ void sobel_pair(float a00, float a01, float a02,
                                           float a10, float a12,
                                           float a20, float a21, float a22,
                                           float& gxv, float& gyv) {
  // Factored form, bit-identical to the reference row-major accumulation
  // (pow-2 scaling and negation commute with round-to-nearest; verified R8).
  float t1 = 0.5f * (a02 - a00);     // == fl(-0.5*a00 + 0.5*a02)
  float t2 = t1 - a10;
  float t3 = t2 + a12;
  float t4 = t3 - 0.5f * a20;
  gxv = t4 + 0.5f * a22;
  float p1 = 0.5f * a00 + a01;       // == -fl(-0.5*a00 - a01)
  float p2 = p1 + 0.5f * a02;        // == -s2
  float u3 = 0.5f * a20 - p2;        // == fl(s2 + 0.5*a20)
  float u4 = u3 + a21;
  gyv = u4 + 0.5f * a22;
}

// Hot path: orientation comparator network + squared-magnitude NMS with
// conservative margin. Uncertain lanes -> exact reference chain, INLINE,
// guarded by a wave-uniform __any branch (skipped ~94% of the time).
__device__ __forceinline__ float decide(float gxv, float gyv, float sc,
                                        float s0a, float s0b, float s1a, float s1b,
                                        float s2a, float s2b, float s3a, float s3b,
                                        float thr, float thr2) {
#pragma clang fp contract(off)
  const float T1 = 0.19891236737965801f, D1 = 5.0e-5f;
  const float T2 = 0.66817863791929898f, D2 = 7.0e-5f;
  const float T3 = 1.49660576266548901f, D3 = 1.5e-4f;
  const float T4 = 5.02733949212584810f, D4 = 1.2e-3f;

  const float av = fabsf(gyv), bv = fabsf(gxv);
  const float c1 = fmaf(-T1, bv, av);
  const float c2 = fmaf(-T2, bv, av);
  const float c3 = fmaf(-T3, bv, av);
  const float c4 = fmaf(-T4, bv, av);
  const bool nearb = (fabsf(c1) < D1 * bv) || (fabsf(c2) < D2 * bv) ||
                     (fabsf(c3) < D3 * bv) || (fabsf(c4) < D4 * bv);

  const unsigned sgn = (__float_as_uint(gyv) ^ __float_as_uint(gxv)) >> 31;
  int d;
  if (c1 < 0.0f)      d = 0;
  else if (c2 < 0.0f) d = sgn ? 3 : 1;
  else if (c3 < 0.0f) d = 2;
  else if (c4 < 0.0f) d = sgn ? 1 : 3;
  else                d = 0;

  const float sn1 = (d == 0) ? s0a : (d == 1) ? s1a : (d == 2) ? s2a : s3a;
  const float sn2 = (d == 0) ? s0b : (d == 1) ? s1b : (d == 2) ? s2b : s3b;

  // raw: sign-exact reject side (sqrt monotone). sure: strict with margin
  // 1-2e-6 (covers the sqrt-tie band + the multiply's own rounding).
  const float scl = sc * 0.999998f;
  const bool raw  = (sc  > sn1) && (sc  > sn2) && (sc  > thr2);
  const bool sure = (scl > sn1) && (scl > sn2) && (scl > thr2);

  const bool need = nearb || (raw != sure);
  float res = sure ? 1.0f : 0.0f;

  if (__builtin_expect(__any((int)need), 0)) {
    // exact reference pipeline (bit-identical to round 0, which passed)
    const float C = (float)(360.0 / M_PI);
    float r  = gyv / gxv;
    float t  = atanf(r);
    float u  = t * C;
    float v2 = u + 180.0f;
    float w  = v2 / 45.0f;
    int   kk = (int)rintf(w);
    int   dd = kk & 3;
    float sn1e = (dd == 0) ? s0a : (dd == 1) ? s1a : (dd == 2) ? s2a : s3a;
    float sn2e = (dd == 0) ? s0b : (dd == 1) ? s1b : (dd == 2) ? s2b : s3b;
    float gmc = sqrtf(sc), n1 = sqrtf(sn1e), n2 = sqrtf(sn2e);
    bool keep = (gmc - n1 > 0.0f) && (gmc - n2 > 0.0f) && (gmc - thr > 0.0f);
    float slow = keep ? 1.0f : 0.0f;
    res = need ? slow : res;
  }
  return res;
}

__global__ __launch_bounds__(256)
void canny_kernel(const float* __restrict__ img, const float* __restrict__ thrp,
                  float* __restrict__ out) {
#pragma clang fp contract(off)
  __shared__ __align__(16) float s_img[IH][IW2];
  __shared__ __align__(16) float s_sq[GH][GSTR];   // squared grad magnitude

  const int b   = blockIdx.z;
  const int bx0 = blockIdx.x * TX;
  const int by0 = blockIdx.y * TY;
  const float* im = img + (size_t)b * (W * H);
  float* ob       = out + (size_t)b * (W * H);
  const int tid = threadIdx.x;
  const bool edge = (bx0 == 0) || (bx0 + TX == W) || (by0 == 0) || (by0 + TY == H);

  // ---- Stage img tile: rows by0-2..by0+17, cols bx0-4..bx0+131, zero outside ----
  // 20 rows x 34 float4 = 680 units; row stride 136 floats = 34 float4 -> LDS
  // destination address is u*16 bytes (fully linear).
  if (!edge) {
    const float* base = im + (size_t)(by0 - 2) * W + (bx0 - 4);
    {
      int u = tid;
      int row = u / 34, col = u - row * 34;
      *reinterpret_cast<float4*>(&s_img[0][0] + u * 4) =
          *reinterpret_cast<const float4*>(base + row * W + col * 4);
    }
    {
      int u = tid + 256;
      int row = u / 34, col = u - row * 34;
      *reinterpret_cast<float4*>(&s_img[0][0] + u * 4) =
          *reinterpret_cast<const float4*>(base + row * W + col * 4);
    }
    {
      int u = tid + 512;
      if (u < 680) {
        int row = u / 34, col = u - row * 34;
        *reinterpret_cast<float4*>(&s_img[0][0] + u * 4) =
            *reinterpret_cast<const float4*>(base + row * W + col * 4);
      }
    }
  } else {
    for (int i = tid; i < IH * IW2; i += 256) {
      int r = i / IW2, cx = i - r * IW2;
      int gy = by0 - 2 + r, gx = bx0 - 4 + cx;
      float v = 0.0f;
      if ((unsigned)gy < 1024u && (unsigned)gx < 1024u) v = im[gy * W + gx];
      s_img[r][cx] = v;
    }
  }
  __syncthreads();

  const int c  = tid & 127;           // owned column (image col bx0+c)
  const int tz = tid >> 7;            // strip: pixel rows 8*tz .. 8*tz+7

  // ---- s2 phase: 10 rows per thread, rows r = 8*tz-1 .. 8*tz+8 ----
  // Window tile rows for step Q: tr0+Q .. tr0+Q+2 with tr0 = 8*tz; col c uses
  // s_img cols c+3..c+5. Rows 7,8 duplicated across strips: identical bits.
  float gq0, gq1, gq2, gq3, gq4, gq5, gq6, gq7, gq8, gq9;
  float gx0, gx1, gx2, gx3, gx4, gx5, gx6, gx7;
  float gy0, gy1, gy2, gy3, gy4, gy5, gy6, gy7;
  {
    const int tr0 = 8 * tz;
    const int rowbase = by0 + tr0 - 1;     // image row at Q=0
    float x0 = s_img[tr0][c + 3],     x1 = s_img[tr0][c + 4],     x2 = s_img[tr0][c + 5];
    float y0 = s_img[tr0 + 1][c + 3], y1 = s_img[tr0 + 1][c + 4], y2 = s_img[tr0 + 1][c + 5];

#define GM_STEP(Q, GQ, SAVE)                                                   \
    {                                                                          \
      float z0 = s_img[tr0 + Q + 2][c + 3];                                    \
      float z1 = s_img[tr0 + Q + 2][c + 4];                                    \
      float z2 = s_img[tr0 + Q + 2][c + 5];                                    \
      float gxv, gyv;                                                          \
      sobel_pair(x0, x1, x2, y0, y2, z0, z1, z2, gxv, gyv);                    \
      float sq = gxv * gxv + gyv * gyv;                                        \
      if (edge) { if ((unsigned)(rowbase + Q) >= 1024u) sq = 0.0f; }           \
      s_sq[tr0 + Q][c + 1] = sq;                                               \
      GQ = sq;                                                                 \
      SAVE;                                                                    \
      x0 = y0; x1 = y1; x2 = y2;                                               \
      y0 = z0; y1 = z1; y2 = z2;                                               \
    }

    GM_STEP(0, gq0, (void)0)
    GM_STEP(1, gq1, ((gx0 = gxv), (gy0 = gyv)))
    GM_STEP(2, gq2, ((gx1 = gxv), (gy1 = gyv)))
    GM_STEP(3, gq3, ((gx2 = gxv), (gy2 = gyv)))
    GM_STEP(4, gq4, ((gx3 = gxv), (gy3 = gyv)))
    GM_STEP(5, gq5, ((gx4 = gxv), (gy4 = gyv)))
    GM_STEP(6, gq6, ((gx5 = gxv), (gy5 = gyv)))
    GM_STEP(7, gq7, ((gx6 = gxv), (gy6 = gyv)))
    GM_STEP(8, gq8, ((gx7 = gxv), (gy7 = gyv)))
    GM_STEP(9, gq9, (void)0)
#undef GM_STEP
  }

  // halo cols c=-1 (p=0) and c=128 (p=129): rows r=-1..16 -> 36 elements
  if (tid < 36) {
    int rr = tid >> 1;                     // 0..17, gm row r = rr-1
    int r  = rr - 1;
    int cc = (tid & 1) ? 128 : -1;
    float gxv, gyv;
    sobel_pair(s_img[rr][cc + 3],     s_img[rr][cc + 4],     s_img[rr][cc + 5],
               s_img[rr + 1][cc + 3],                        s_img[rr + 1][cc + 5],
               s_img[rr + 2][cc + 3], s_img[rr + 2][cc + 4], s_img[rr + 2][cc + 5],
               gxv, gyv);
    float sq = gxv * gxv + gyv * gyv;
    if (!((unsigned)(by0 + r) < 1024u && (unsigned)(bx0 + cc) < 1024u)) sq = 0.0f;
    s_sq[rr][cc + 1] = sq;
  }
  __syncthreads();

  // ---- pixel phase: 8-pixel column per thread ----
  // L_k / R_k = s2 of cols c-1 / c+1 at gm row 8*tz-1+k  (s_sq idx 8*tz+k).
  {
    const float thr  = *thrp;
    const float thr2 = thr * thr;
    const int gb = 8 * tz;
    const float L0 = s_sq[gb + 0][c], R0 = s_sq[gb + 0][c + 2];
    const float L1 = s_sq[gb + 1][c], R1 = s_sq[gb + 1][c + 2];
    const float L2 = s_sq[gb + 2][c], R2 = s_sq[gb + 2][c + 2];
    const float L3 = s_sq[gb + 3][c], R3 = s_sq[gb + 3][c + 2];
    const float L4 = s_sq[gb + 4][c], R4 = s_sq[gb + 4][c + 2];
    const float L5 = s_sq[gb + 5][c], R5 = s_sq[gb + 5][c + 2];
    const float L6 = s_sq[gb + 6][c], R6 = s_sq[gb + 6][c + 2];
    const float L7 = s_sq[gb + 7][c], R7 = s_sq[gb + 7][c + 2];
    const float L8 = s_sq[gb + 8][c], R8 = s_sq[gb + 8][c + 2];
    const float L9 = s_sq[gb + 9][c], R9 = s_sq[gb + 9][c + 2];

    float* orow = ob + (size_t)(by0 + gb) * W + bx0 + c;

    // pixel k: sc=gq[k+1]; d0:(R[k+1],L[k+1]) d1:(R[k],L[k+2])
    //          d2:(gq[k],gq[k+2]) d3:(L[k],R[k+2])
    orow[0 * W] = decide(gx0, gy0, gq1, R1, L1, R0, L2, gq0, gq2, L0, R2, thr, thr2);
    orow[1 * W] = decide(gx1, gy1, gq2, R2, L2, R1, L3, gq1, gq3, L1, R3, thr, thr2);
    orow[2 * W] = decide(gx2, gy2, gq3, R3, L3, R2, L4, gq2, gq4, L2, R4, thr, thr2);
    orow[3 * W] = decide(gx3, gy3, gq4, R4, L4, R3, L5, gq3, gq5, L3, R5, thr, thr2);
    orow[4 * W] = decide(gx4, gy4, gq5, R5, L5, R4, L6, gq4, gq6, L4, R6, thr, thr2);
    orow[5 * W] = decide(gx5, gy5, gq6, R6, L6, R5, L7, gq5, gq7, L5, R7, thr, thr2);
    orow[6 * W] = decide(gx6, gy6, gq7, R7, L7, R6, L8, gq6, gq8, L6, R8, thr, thr2);
    orow[7 * W] = decide(gx7, gy7, gq8, R8, L8, R7, L9, gq7, gq9, L7, R9, thr, thr2);
  }
}

extern "C" void kernel_launch(void* const* d_in, const int* in_sizes, int n_in,
                              void* d_out, int out_size, void* d_ws, size_t ws_size,
                              hipStream_t stream) {
  const float* img = (const float*)d_in[0];
  const float* thr = (const float*)d_in[4];
  float* out = (float*)d_out;
  const int batch = in_sizes[0] / (W * H);

  dim3 grid(W / TX, H / TY, batch);
  canny_kernel<<<grid, dim3(256), 0, stream>>>(img, thr, out);
}

// Round 11
// 53.589 us; speedup vs baseline: 1.0858x; 1.0299x over previous
//
#include <hip/hip_runtime.h>
#include <math.h>

// SurrogateCanny fused kernel, round 10.
// R9 showed VALU cuts don't move the wall -> stall-bound, not VALU-bound.
// The gm phase's rolling GM_STEP serializes {3 LDS reads -> sobel} x10
// (ds_read latency ~120cyc, VGPR=36 proves no hoisting). This round:
// full-unroll gm phase with all 33 img loads issued upfront (batched
// latency), and a 9/9 row split (no duplicated junction rows; each strip
// reads its 10th row from LDS after the barrier). decide()/staging/halo
// byte-identical to R9 (passed absmax 0).

constexpr int W = 1024, H = 1024;
constexpr int TX = 128, TY = 16;         // output tile per block (256 threads)
constexpr int IH = TY + 4, IW2 = 136;    // img tile: rows by0-2..by0+17, cols bx0-4..bx0+131
constexpr int GH = TY + 2, GSTR = 132;   // s2 plane: rows r=-1..16 (idx r+1), cols p=c+1

__device__ __forceinline__ void sobel_pair(float a00, float a01, float a02,
                                           float a10, float a12,
                                           float a20, float a21, float a22,
                                           float& gxv, float& gyv) {
  // Factored form, bit-identical to the reference row-major accumulation
  // (pow-2 scaling and negation commute with round-to-nearest; verified R8/R9).
  float t1 = 0.5f * (a02 - a00);     // == fl(-0.5*a00 + 0.5*a02)
  float t2 = t1 - a10;
  float t3 = t2 + a12;
  float t4 = t3 - 0.5f * a20;
  gxv = t4 + 0.5f * a22;
  float p1 = 0.5f * a00 + a01;       // == -fl(-0.5*a00 - a01)
  float p2 = p1 + 0.5f * a02;        // == -s2
  float u3 = 0.5f * a20 - p2;        // == fl(s2 + 0.5*a20)
  float u4 = u3 + a21;
  gyv = u4 + 0.5f * a22;
}

// Hot path: orientation comparator network + squared-magnitude NMS with
// conservative margin. Uncertain lanes -> exact reference chain, INLINE,
// guarded by a wave-uniform __any branch. Verbatim from R9 (passed).
__device__ __forceinline__ float decide(float gxv, float gyv, float sc,
                                        float s0a, float s0b, float s1a, float s1b,
                                        float s2a, float s2b, float s3a, float s3b,
                                        float thr, float thr2) {
#pragma clang fp contract(off)
  const float T1 = 0.19891236737965801f, D1 = 5.0e-5f;
  const float T2 = 0.66817863791929898f, D2 = 7.0e-5f;
  const float T3 = 1.49660576266548901f, D3 = 1.5e-4f;
  const float T4 = 5.02733949212584810f, D4 = 1.2e-3f;

  const float av = fabsf(gyv), bv = fabsf(gxv);
  const float c1 = fmaf(-T1, bv, av);
  const float c2 = fmaf(-T2, bv, av);
  const float c3 = fmaf(-T3, bv, av);
  const float c4 = fmaf(-T4, bv, av);
  const bool nearb = (fabsf(c1) < D1 * bv) || (fabsf(c2) < D2 * bv) ||
                     (fabsf(c3) < D3 * bv) || (fabsf(c4) < D4 * bv);

  const unsigned sgn = (__float_as_uint(gyv) ^ __float_as_uint(gxv)) >> 31;
  int d;
  if (c1 < 0.0f)      d = 0;
  else if (c2 < 0.0f) d = sgn ? 3 : 1;
  else if (c3 < 0.0f) d = 2;
  else if (c4 < 0.0f) d = sgn ? 1 : 3;
  else                d = 0;

  const float sn1 = (d == 0) ? s0a : (d == 1) ? s1a : (d == 2) ? s2a : s3a;
  const float sn2 = (d == 0) ? s0b : (d == 1) ? s1b : (d == 2) ? s2b : s3b;

  const float scl = sc * 0.999998f;
  const bool raw  = (sc  > sn1) && (sc  > sn2) && (sc  > thr2);
  const bool sure = (scl > sn1) && (scl > sn2) && (scl > thr2);

  const bool need = nearb || (raw != sure);
  float res = sure ? 1.0f : 0.0f;

  if (__builtin_expect(__any((int)need), 0)) {
    const float C = (float)(360.0 / M_PI);
    float r  = gyv / gxv;
    float t  = atanf(r);
    float u  = t * C;
    float v2 = u + 180.0f;
    float w  = v2 / 45.0f;
    int   kk = (int)rintf(w);
    int   dd = kk & 3;
    float sn1e = (dd == 0) ? s0a : (dd == 1) ? s1a : (dd == 2) ? s2a : s3a;
    float sn2e = (dd == 0) ? s0b : (dd == 1) ? s1b : (dd == 2) ? s2b : s3b;
    float gmc = sqrtf(sc), n1 = sqrtf(sn1e), n2 = sqrtf(sn2e);
    bool keep = (gmc - n1 > 0.0f) && (gmc - n2 > 0.0f) && (gmc - thr > 0.0f);
    float slow = keep ? 1.0f : 0.0f;
    res = need ? slow : res;
  }
  return res;
}

__global__ __launch_bounds__(256)
void canny_kernel(const float* __restrict__ img, const float* __restrict__ thrp,
                  float* __restrict__ out) {
#pragma clang fp contract(off)
  __shared__ __align__(16) float s_img[IH][IW2];
  __shared__ __align__(16) float s_sq[GH][GSTR];   // squared grad magnitude

  const int b   = blockIdx.z;
  const int bx0 = blockIdx.x * TX;
  const int by0 = blockIdx.y * TY;
  const float* im = img + (size_t)b * (W * H);
  float* ob       = out + (size_t)b * (W * H);
  const int tid = threadIdx.x;
  const bool edge = (bx0 == 0) || (bx0 + TX == W) || (by0 == 0) || (by0 + TY == H);

  // ---- Stage img tile: rows by0-2..by0+17, cols bx0-4..bx0+131, zero outside ----
  if (!edge) {
    const float* base = im + (size_t)(by0 - 2) * W + (bx0 - 4);
    {
      int u = tid;
      int row = u / 34, col = u - row * 34;
      *reinterpret_cast<float4*>(&s_img[0][0] + u * 4) =
          *reinterpret_cast<const float4*>(base + row * W + col * 4);
    }
    {
      int u = tid + 256;
      int row = u / 34, col = u - row * 34;
      *reinterpret_cast<float4*>(&s_img[0][0] + u * 4) =
          *reinterpret_cast<const float4*>(base + row * W + col * 4);
    }
    {
      int u = tid + 512;
      if (u < 680) {
        int row = u / 34, col = u - row * 34;
        *reinterpret_cast<float4*>(&s_img[0][0] + u * 4) =
            *reinterpret_cast<const float4*>(base + row * W + col * 4);
      }
    }
  } else {
    for (int i = tid; i < IH * IW2; i += 256) {
      int r = i / IW2, cx = i - r * IW2;
      int gy = by0 - 2 + r, gx = bx0 - 4 + cx;
      float v = 0.0f;
      if ((unsigned)gy < 1024u && (unsigned)gx < 1024u) v = im[gy * W + gx];
      s_img[r][cx] = v;
    }
  }
  __syncthreads();

  const int c  = tid & 127;           // owned column (image col bx0+c)
  const int tz = tid >> 7;            // wave-uniform strip id (0 or 1)
  const int k0 = 9 * tz;              // first s_sq row idx this thread computes

  // ---- gm phase, fully unrolled: 33 LDS loads upfront, then 9 sobels ----
  // s_sq idx k = k0+j (j=0..8), gm row r = k-1, image row by0 + k - 1.
  // Window uses s_img rows k0+j .. k0+j+2, cols c+3..c+5.
  const float iA0  = s_img[k0 + 0][c + 3],  iB0  = s_img[k0 + 0][c + 4],  iC0  = s_img[k0 + 0][c + 5];
  const float iA1  = s_img[k0 + 1][c + 3],  iB1  = s_img[k0 + 1][c + 4],  iC1  = s_img[k0 + 1][c + 5];
  const float iA2  = s_img[k0 + 2][c + 3],  iB2  = s_img[k0 + 2][c + 4],  iC2  = s_img[k0 + 2][c + 5];
  const float iA3  = s_img[k0 + 3][c + 3],  iB3  = s_img[k0 + 3][c + 4],  iC3  = s_img[k0 + 3][c + 5];
  const float iA4  = s_img[k0 + 4][c + 3],  iB4  = s_img[k0 + 4][c + 4],  iC4  = s_img[k0 + 4][c + 5];
  const float iA5  = s_img[k0 + 5][c + 3],  iB5  = s_img[k0 + 5][c + 4],  iC5  = s_img[k0 + 5][c + 5];
  const float iA6  = s_img[k0 + 6][c + 3],  iB6  = s_img[k0 + 6][c + 4],  iC6  = s_img[k0 + 6][c + 5];
  const float iA7  = s_img[k0 + 7][c + 3],  iB7  = s_img[k0 + 7][c + 4],  iC7  = s_img[k0 + 7][c + 5];
  const float iA8  = s_img[k0 + 8][c + 3],  iB8  = s_img[k0 + 8][c + 4],  iC8  = s_img[k0 + 8][c + 5];
  const float iA9  = s_img[k0 + 9][c + 3],  iB9  = s_img[k0 + 9][c + 4],  iC9  = s_img[k0 + 9][c + 5];
  const float iA10 = s_img[k0 + 10][c + 3], iB10 = s_img[k0 + 10][c + 4], iC10 = s_img[k0 + 10][c + 5];

  const int rowim0 = by0 + k0 - 1;    // image row of s_sq idx k0

  float t0, t1, t2, t3, t4, t5, t6, t7, t8;
  float sx0, sx1, sx2, sx3, sx4, sx5, sx6, sx7, sx8;
  float sy0, sy1, sy2, sy3, sy4, sy5, sy6, sy7, sy8;

#define GM_ROW(J, A0, B0, C0, A1, C1, A2, B2, C2, T, SX, SY)                   \
  {                                                                            \
    float gxv, gyv;                                                            \
    sobel_pair(A0, B0, C0, A1, C1, A2, B2, C2, gxv, gyv);                      \
    float sq = gxv * gxv + gyv * gyv;                                          \
    if (edge) { if ((unsigned)(rowim0 + J) >= 1024u) sq = 0.0f; }              \
    s_sq[k0 + J][c + 1] = sq;                                                  \
    T = sq; SX = gxv; SY = gyv;                                                \
  }

  GM_ROW(0, iA0, iB0, iC0, iA1, iC1, iA2, iB2, iC2, t0, sx0, sy0)
  GM_ROW(1, iA1, iB1, iC1, iA2, iC2, iA3, iB3, iC3, t1, sx1, sy1)
  GM_ROW(2, iA2, iB2, iC2, iA3, iC3, iA4, iB4, iC4, t2, sx2, sy2)
  GM_ROW(3, iA3, iB3, iC3, iA4, iC4, iA5, iB5, iC5, t3, sx3, sy3)
  GM_ROW(4, iA4, iB4, iC4, iA5, iC5, iA6, iB6, iC6, t4, sx4, sy4)
  GM_ROW(5, iA5, iB5, iC5, iA6, iC6, iA7, iB7, iC7, t5, sx5, sy5)
  GM_ROW(6, iA6, iB6, iC6, iA7, iC7, iA8, iB8, iC8, t6, sx6, sy6)
  GM_ROW(7, iA7, iB7, iC7, iA8, iC8, iA9, iB9, iC9, t7, sx7, sy7)
  GM_ROW(8, iA8, iB8, iC8, iA9, iC9, iA10, iB10, iC10, t8, sx8, sy8)
#undef GM_ROW

  // halo cols c=-1 (p=0) and c=128 (p=129): rows r=-1..16 -> 36 elements
  if (tid < 36) {
    int rr = tid >> 1;                     // 0..17, gm row r = rr-1
    int r  = rr - 1;
    int cc = (tid & 1) ? 128 : -1;
    float gxv, gyv;
    sobel_pair(s_img[rr][cc + 3],     s_img[rr][cc + 4],     s_img[rr][cc + 5],
               s_img[rr + 1][cc + 3],                        s_img[rr + 1][cc + 5],
               s_img[rr + 2][cc + 3], s_img[rr + 2][cc + 4], s_img[rr + 2][cc + 5],
               gxv, gyv);
    float sq = gxv * gxv + gyv * gyv;
    if (!((unsigned)(by0 + r) < 1024u && (unsigned)(bx0 + cc) < 1024u)) sq = 0.0f;
    s_sq[rr][cc + 1] = sq;
  }
  __syncthreads();

  // ---- pixel phase: 8-pixel column per thread ----
  {
    const float thr  = *thrp;
    const float thr2 = thr * thr;
    const int gb = 8 * tz;
    // L/R neighbor columns for s_sq idx gb+0 .. gb+9
    const float L0 = s_sq[gb + 0][c], R0 = s_sq[gb + 0][c + 2];
    const float L1 = s_sq[gb + 1][c], R1 = s_sq[gb + 1][c + 2];
    const float L2 = s_sq[gb + 2][c], R2 = s_sq[gb + 2][c + 2];
    const float L3 = s_sq[gb + 3][c], R3 = s_sq[gb + 3][c + 2];
    const float L4 = s_sq[gb + 4][c], R4 = s_sq[gb + 4][c + 2];
    const float L5 = s_sq[gb + 5][c], R5 = s_sq[gb + 5][c + 2];
    const float L6 = s_sq[gb + 6][c], R6 = s_sq[gb + 6][c + 2];
    const float L7 = s_sq[gb + 7][c], R7 = s_sq[gb + 7][c + 2];
    const float L8 = s_sq[gb + 8][c], R8 = s_sq[gb + 8][c + 2];
    const float L9 = s_sq[gb + 9][c], R9 = s_sq[gb + 9][c + 2];

    // Own-column s2 (q0..q9 = s_sq idx gb+0..gb+9) and per-pixel gx/gy.
    // tz=0: computed idx 0..8 (t0..t8) -> q0..q8; q9 read (written by tz=1).
    //       pixels centers idx 1..8 -> X/Y = sx1..sx8.
    // tz=1: computed idx 9..17 (t0..t8) -> q1..q9; q0 read (idx 8, by tz=0).
    //       pixels centers idx 9..16 -> X/Y = sx0..sx7.
    float q0, q1, q2, q3, q4, q5, q6, q7, q8, q9;
    float X0, X1, X2, X3, X4, X5, X6, X7;
    float Y0, Y1, Y2, Y3, Y4, Y5, Y6, Y7;
    if (tz == 0) {
      q0 = t0; q1 = t1; q2 = t2; q3 = t3; q4 = t4;
      q5 = t5; q6 = t6; q7 = t7; q8 = t8;
      q9 = s_sq[9][c + 1];
      X0 = sx1; X1 = sx2; X2 = sx3; X3 = sx4; X4 = sx5; X5 = sx6; X6 = sx7; X7 = sx8;
      Y0 = sy1; Y1 = sy2; Y2 = sy3; Y3 = sy4; Y4 = sy5; Y5 = sy6; Y6 = sy7; Y7 = sy8;
    } else {
      q0 = s_sq[8][c + 1];
      q1 = t0; q2 = t1; q3 = t2; q4 = t3; q5 = t4;
      q6 = t5; q7 = t6; q8 = t7; q9 = t8;
      X0 = sx0; X1 = sx1; X2 = sx2; X3 = sx3; X4 = sx4; X5 = sx5; X6 = sx6; X7 = sx7;
      Y0 = sy0; Y1 = sy1; Y2 = sy2; Y3 = sy3; Y4 = sy4; Y5 = sy5; Y6 = sy6; Y7 = sy7;
    }

    float* orow = ob + (size_t)(by0 + gb) * W + bx0 + c;

    // pixel k: sc=q[k+1]; d0:(R[k+1],L[k+1]) d1:(R[k],L[k+2])
    //          d2:(q[k],q[k+2]) d3:(L[k],R[k+2])
    orow[0 * W] = decide(X0, Y0, q1, R1, L1, R0, L2, q0, q2, L0, R2, thr, thr2);
    orow[1 * W] = decide(X1, Y1, q2, R2, L2, R1, L3, q1, q3, L1, R3, thr, thr2);
    orow[2 * W] = decide(X2, Y2, q3, R3, L3, R2, L4, q2, q4, L2, R4, thr, thr2);
    orow[3 * W] = decide(X3, Y3, q4, R4, L4, R3, L5, q3, q5, L3, R5, thr, thr2);
    orow[4 * W] = decide(X4, Y4, q5, R5, L5, R4, L6, q4, q6, L4, R6, thr, thr2);
    orow[5 * W] = decide(X5, Y5, q6, R6, L6, R5, L7, q5, q7, L5, R7, thr, thr2);
    orow[6 * W] = decide(X6, Y6, q7, R7, L7, R6, L8, q6, q8, L6, R8, thr, thr2);
    orow[7 * W] = decide(X7, Y7, q8, R8, L8, R7, L9, q7, q9, L7, R9, thr, thr2);
  }
}

extern "C" void kernel_launch(void* const* d_in, const int* in_sizes, int n_in,
                              void* d_out, int out_size, void* d_ws, size_t ws_size,
                              hipStream_t stream) {
  const float* img = (const float*)d_in[0];
  const float* thr = (const float*)d_in[4];
  float* out = (float*)d_out;
  const int batch = in_sizes[0] / (W * H);

  dim3 grid(W / TX, H / TY, batch);
  canny_kernel<<<grid, dim3(256), 0, stream>>>(img, thr, out);
}

// Round 12
// 42.861 us; speedup vs baseline: 1.3576x; 1.2503x over previous
//
#include <hip/hip_runtime.h>
#include <math.h>

// SurrogateCanny fused kernel, round 11.
// R8-R10 showed VALU cuts don't move the ~60us wall: VALU (~38us) + LDS pipe
// (~16us) barely overlap because the staged global->LDS->VGPR pipeline and
// two barriers keep waves phase-locked. This round: delete s_img staging and
// barrier 1 entirely -- Sobel inputs load directly from global (coalesced,
// L2/L3-resident on replays), LDS holds only s_sq. decide() slimmed via exact
// max3 identity (sc>a && sc>b && sc>thr2 <=> sc>max3). GM_ROW / halo / pixel
// phase / slow path verbatim from R10 (passed absmax 0).

constexpr int W = 1024, H = 1024;
constexpr int TX = 128, TY = 16;         // output tile per block (256 threads)
constexpr int GH = TY + 2, GSTR = 132;   // s2 plane: rows r=-1..16 (idx r+1), cols p=c+1

__device__ __forceinline__ void sobel_pair(float a00, float a01, float a02,
                                           float a10, float a12,
                                           float a20, float a21, float a22,
                                           float& gxv, float& gyv) {
  // Factored form, bit-identical to the reference row-major accumulation
  // (pow-2 scaling and negation commute with round-to-nearest; verified R8-R10).
  float t1 = 0.5f * (a02 - a00);     // == fl(-0.5*a00 + 0.5*a02)
  float t2 = t1 - a10;
  float t3 = t2 + a12;
  float t4 = t3 - 0.5f * a20;
  gxv = t4 + 0.5f * a22;
  float p1 = 0.5f * a00 + a01;       // == -fl(-0.5*a00 - a01)
  float p2 = p1 + 0.5f * a02;        // == -s2
  float u3 = 0.5f * a20 - p2;        // == fl(s2 + 0.5*a20)
  float u4 = u3 + a21;
  gyv = u4 + 0.5f * a22;
}

// Guarded global load with clamped address (never faults; 0 outside image),
// reproducing the zero-padding semantics s_img provided.
__device__ __forceinline__ float gld(const float* __restrict__ im, int r, int c) {
  const bool ok = ((unsigned)r < 1024u) && ((unsigned)c < 1024u);
  const int rc = min(max(r, 0), 1023);
  const int cc = min(max(c, 0), 1023);
  const float v = im[rc * W + cc];
  return ok ? v : 0.0f;
}

// Hot path: orientation comparator network + squared-magnitude NMS with
// conservative margin, via exact max3 identity. Uncertain lanes -> exact
// reference chain, INLINE, behind a wave-uniform __any branch (as R9/R10).
__device__ __forceinline__ float decide(float gxv, float gyv, float sc,
                                        float s0a, float s0b, float s1a, float s1b,
                                        float s2a, float s2b, float s3a, float s3b,
                                        float thr, float thr2) {
#pragma clang fp contract(off)
  const float T1 = 0.19891236737965801f, D1 = 5.0e-5f;
  const float T2 = 0.66817863791929898f, D2 = 7.0e-5f;
  const float T3 = 1.49660576266548901f, D3 = 1.5e-4f;
  const float T4 = 5.02733949212584810f, D4 = 1.2e-3f;

  const float av = fabsf(gyv), bv = fabsf(gxv);
  const float c1 = fmaf(-T1, bv, av);
  const float c2 = fmaf(-T2, bv, av);
  const float c3 = fmaf(-T3, bv, av);
  const float c4 = fmaf(-T4, bv, av);
  const bool nearb = (fabsf(c1) < D1 * bv) || (fabsf(c2) < D2 * bv) ||
                     (fabsf(c3) < D3 * bv) || (fabsf(c4) < D4 * bv);

  const unsigned sgn = (__float_as_uint(gyv) ^ __float_as_uint(gxv)) >> 31;

  // per-direction max of {n1, n2, thr2}: keep_d <=> sc > m_d (exact identity)
  const float m0 = fmaxf(fmaxf(s0a, s0b), thr2);
  const float m1 = fmaxf(fmaxf(s1a, s1b), thr2);
  const float m2 = fmaxf(fmaxf(s2a, s2b), thr2);
  const float m3 = fmaxf(fmaxf(s3a, s3b), thr2);
  float m;
  if (c1 < 0.0f)      m = m0;
  else if (c2 < 0.0f) m = sgn ? m3 : m1;
  else if (c3 < 0.0f) m = m2;
  else if (c4 < 0.0f) m = sgn ? m1 : m3;
  else                m = m0;

  const float scl = sc * 0.999998f;
  const bool raw  = (sc  > m);
  const bool sure = (scl > m);

  const bool need = nearb || (raw != sure);
  float res = sure ? 1.0f : 0.0f;

  if (__builtin_expect(__any((int)need), 0)) {
    const float C = (float)(360.0 / M_PI);
    float r  = gyv / gxv;
    float t  = atanf(r);
    float u  = t * C;
    float v2 = u + 180.0f;
    float w  = v2 / 45.0f;
    int   kk = (int)rintf(w);
    int   dd = kk & 3;
    float sn1e = (dd == 0) ? s0a : (dd == 1) ? s1a : (dd == 2) ? s2a : s3a;
    float sn2e = (dd == 0) ? s0b : (dd == 1) ? s1b : (dd == 2) ? s2b : s3b;
    float gmc = sqrtf(sc), n1 = sqrtf(sn1e), n2 = sqrtf(sn2e);
    bool keep = (gmc - n1 > 0.0f) && (gmc - n2 > 0.0f) && (gmc - thr > 0.0f);
    float slow = keep ? 1.0f : 0.0f;
    res = need ? slow : res;
  }
  return res;
}

__global__ __launch_bounds__(256)
void canny_kernel(const float* __restrict__ img, const float* __restrict__ thrp,
                  float* __restrict__ out) {
#pragma clang fp contract(off)
  __shared__ __align__(16) float s_sq[GH][GSTR];   // squared grad magnitude

  const int b   = blockIdx.z;
  const int bx0 = blockIdx.x * TX;
  const int by0 = blockIdx.y * TY;
  const float* im = img + (size_t)b * (W * H);
  float* ob       = out + (size_t)b * (W * H);
  const int tid = threadIdx.x;
  const bool edge = (bx0 == 0) || (bx0 + TX == W) || (by0 == 0) || (by0 + TY == H);

  const int c  = tid & 127;           // owned column (image col bx0+c)
  const int tz = tid >> 7;            // wave-uniform strip id (0 or 1)
  const int k0 = 9 * tz;              // first s_sq row idx this thread computes

  // ---- load 11 rows x 3 cols of img directly from global ----
  // s_img[k0+j][c+3+d] of R10  ==  img[by0 + k0 - 2 + j][bx0 + c - 1 + d].
  float iA0, iB0, iC0, iA1, iB1, iC1, iA2, iB2, iC2, iA3, iB3, iC3;
  float iA4, iB4, iC4, iA5, iB5, iC5, iA6, iB6, iC6, iA7, iB7, iC7;
  float iA8, iB8, iC8, iA9, iB9, iC9, iA10, iB10, iC10;
  if (!edge) {
    const float* p = im + (size_t)(by0 + k0 - 2) * W + (bx0 + c - 1);
    iA0  = p[0 * W + 0];  iB0  = p[0 * W + 1];  iC0  = p[0 * W + 2];
    iA1  = p[1 * W + 0];  iB1  = p[1 * W + 1];  iC1  = p[1 * W + 2];
    iA2  = p[2 * W + 0];  iB2  = p[2 * W + 1];  iC2  = p[2 * W + 2];
    iA3  = p[3 * W + 0];  iB3  = p[3 * W + 1];  iC3  = p[3 * W + 2];
    iA4  = p[4 * W + 0];  iB4  = p[4 * W + 1];  iC4  = p[4 * W + 2];
    iA5  = p[5 * W + 0];  iB5  = p[5 * W + 1];  iC5  = p[5 * W + 2];
    iA6  = p[6 * W + 0];  iB6  = p[6 * W + 1];  iC6  = p[6 * W + 2];
    iA7  = p[7 * W + 0];  iB7  = p[7 * W + 1];  iC7  = p[7 * W + 2];
    iA8  = p[8 * W + 0];  iB8  = p[8 * W + 1];  iC8  = p[8 * W + 2];
    iA9  = p[9 * W + 0];  iB9  = p[9 * W + 1];  iC9  = p[9 * W + 2];
    iA10 = p[10 * W + 0]; iB10 = p[10 * W + 1]; iC10 = p[10 * W + 2];
  } else {
    const int r0 = by0 + k0 - 2;
    const int cb = bx0 + c;
    iA0  = gld(im, r0 + 0, cb - 1);  iB0  = gld(im, r0 + 0, cb);  iC0  = gld(im, r0 + 0, cb + 1);
    iA1  = gld(im, r0 + 1, cb - 1);  iB1  = gld(im, r0 + 1, cb);  iC1  = gld(im, r0 + 1, cb + 1);
    iA2  = gld(im, r0 + 2, cb - 1);  iB2  = gld(im, r0 + 2, cb);  iC2  = gld(im, r0 + 2, cb + 1);
    iA3  = gld(im, r0 + 3, cb - 1);  iB3  = gld(im, r0 + 3, cb);  iC3  = gld(im, r0 + 3, cb + 1);
    iA4  = gld(im, r0 + 4, cb - 1);  iB4  = gld(im, r0 + 4, cb);  iC4  = gld(im, r0 + 4, cb + 1);
    iA5  = gld(im, r0 + 5, cb - 1);  iB5  = gld(im, r0 + 5, cb);  iC5  = gld(im, r0 + 5, cb + 1);
    iA6  = gld(im, r0 + 6, cb - 1);  iB6  = gld(im, r0 + 6, cb);  iC6  = gld(im, r0 + 6, cb + 1);
    iA7  = gld(im, r0 + 7, cb - 1);  iB7  = gld(im, r0 + 7, cb);  iC7  = gld(im, r0 + 7, cb + 1);
    iA8  = gld(im, r0 + 8, cb - 1);  iB8  = gld(im, r0 + 8, cb);  iC8  = gld(im, r0 + 8, cb + 1);
    iA9  = gld(im, r0 + 9, cb - 1);  iB9  = gld(im, r0 + 9, cb);  iC9  = gld(im, r0 + 9, cb + 1);
    iA10 = gld(im, r0 + 10, cb - 1); iB10 = gld(im, r0 + 10, cb); iC10 = gld(im, r0 + 10, cb + 1);
  }

  const int rowim0 = by0 + k0 - 1;    // image row of s_sq idx k0

  float t0, t1, t2, t3, t4, t5, t6, t7, t8;
  float sx0, sx1, sx2, sx3, sx4, sx5, sx6, sx7, sx8;
  float sy0, sy1, sy2, sy3, sy4, sy5, sy6, sy7, sy8;

#define GM_ROW(J, A0, B0, C0, A1, C1, A2, B2, C2, T, SX, SY)                   \
  {                                                                            \
    float gxv, gyv;                                                            \
    sobel_pair(A0, B0, C0, A1, C1, A2, B2, C2, gxv, gyv);                      \
    float sq = gxv * gxv + gyv * gyv;                                          \
    if (edge) { if ((unsigned)(rowim0 + J) >= 1024u) sq = 0.0f; }              \
    s_sq[k0 + J][c + 1] = sq;                                                  \
    T = sq; SX = gxv; SY = gyv;                                                \
  }

  GM_ROW(0, iA0, iB0, iC0, iA1, iC1, iA2, iB2, iC2, t0, sx0, sy0)
  GM_ROW(1, iA1, iB1, iC1, iA2, iC2, iA3, iB3, iC3, t1, sx1, sy1)
  GM_ROW(2, iA2, iB2, iC2, iA3, iC3, iA4, iB4, iC4, t2, sx2, sy2)
  GM_ROW(3, iA3, iB3, iC3, iA4, iC4, iA5, iB5, iC5, t3, sx3, sy3)
  GM_ROW(4, iA4, iB4, iC4, iA5, iC5, iA6, iB6, iC6, t4, sx4, sy4)
  GM_ROW(5, iA5, iB5, iC5, iA6, iC6, iA7, iB7, iC7, t5, sx5, sy5)
  GM_ROW(6, iA6, iB6, iC6, iA7, iC7, iA8, iB8, iC8, t6, sx6, sy6)
  GM_ROW(7, iA7, iB7, iC7, iA8, iC8, iA9, iB9, iC9, t7, sx7, sy7)
  GM_ROW(8, iA8, iB8, iC8, iA9, iC9, iA10, iB10, iC10, t8, sx8, sy8)
#undef GM_ROW

  // halo cols c=-1 (p=0) and c=128 (p=129): rows r=-1..16 -> 36 elements
  if (tid < 36) {
    int rr = tid >> 1;                     // 0..17, gm row r = rr-1
    int r  = rr - 1;
    int cc = (tid & 1) ? 128 : -1;
    int hr = by0 - 2 + rr;                 // image row of window top
    int hc = bx0 + cc;                     // image col of window center
    float gxv, gyv;
    sobel_pair(gld(im, hr, hc - 1),     gld(im, hr, hc),     gld(im, hr, hc + 1),
               gld(im, hr + 1, hc - 1),                      gld(im, hr + 1, hc + 1),
               gld(im, hr + 2, hc - 1), gld(im, hr + 2, hc), gld(im, hr + 2, hc + 1),
               gxv, gyv);
    float sq = gxv * gxv + gyv * gyv;
    if (!((unsigned)(by0 + r) < 1024u && (unsigned)(bx0 + cc) < 1024u)) sq = 0.0f;
    s_sq[rr][cc + 1] = sq;
  }
  __syncthreads();

  // ---- pixel phase: 8-pixel column per thread (verbatim R10) ----
  {
    const float thr  = *thrp;
    const float thr2 = thr * thr;
    const int gb = 8 * tz;
    const float L0 = s_sq[gb + 0][c], R0 = s_sq[gb + 0][c + 2];
    const float L1 = s_sq[gb + 1][c], R1 = s_sq[gb + 1][c + 2];
    const float L2 = s_sq[gb + 2][c], R2 = s_sq[gb + 2][c + 2];
    const float L3 = s_sq[gb + 3][c], R3 = s_sq[gb + 3][c + 2];
    const float L4 = s_sq[gb + 4][c], R4 = s_sq[gb + 4][c + 2];
    const float L5 = s_sq[gb + 5][c], R5 = s_sq[gb + 5][c + 2];
    const float L6 = s_sq[gb + 6][c], R6 = s_sq[gb + 6][c + 2];
    const float L7 = s_sq[gb + 7][c], R7 = s_sq[gb + 7][c + 2];
    const float L8 = s_sq[gb + 8][c], R8 = s_sq[gb + 8][c + 2];
    const float L9 = s_sq[gb + 9][c], R9 = s_sq[gb + 9][c + 2];

    float q0, q1, q2, q3, q4, q5, q6, q7, q8, q9;
    float X0, X1, X2, X3, X4, X5, X6, X7;
    float Y0, Y1, Y2, Y3, Y4, Y5, Y6, Y7;
    if (tz == 0) {
      q0 = t0; q1 = t1; q2 = t2; q3 = t3; q4 = t4;
      q5 = t5; q6 = t6; q7 = t7; q8 = t8;
      q9 = s_sq[9][c + 1];
      X0 = sx1; X1 = sx2; X2 = sx3; X3 = sx4; X4 = sx5; X5 = sx6; X6 = sx7; X7 = sx8;
      Y0 = sy1; Y1 = sy2; Y2 = sy3; Y3 = sy4; Y4 = sy5; Y5 = sy6; Y6 = sy7; Y7 = sy8;
    } else {
      q0 = s_sq[8][c + 1];
      q1 = t0; q2 = t1; q3 = t2; q4 = t3; q5 = t4;
      q6 = t5; q7 = t6; q8 = t7; q9 = t8;
      X0 = sx0; X1 = sx1; X2 = sx2; X3 = sx3; X4 = sx4; X5 = sx5; X6 = sx6; X7 = sx7;
      Y0 = sy0; Y1 = sy1; Y2 = sy2; Y3 = sy3; Y4 = sy4; Y5 = sy5; Y6 = sy7 - (sy7 - sy6) - (sy6 - sy6); // placeholder guard
      Y6 = sy6; Y7 = sy7;
    }

    float* orow = ob + (size_t)(by0 + gb) * W + bx0 + c;

    // pixel k: sc=q[k+1]; d0:(R[k+1],L[k+1]) d1:(R[k],L[k+2])
    //          d2:(q[k],q[k+2]) d3:(L[k],R[k+2])
    orow[0 * W] = decide(X0, Y0, q1, R1, L1, R0, L2, q0, q2, L0, R2, thr, thr2);
    orow[1 * W] = decide(X1, Y1, q2, R2, L2, R1, L3, q1, q3, L1, R3, thr, thr2);
    orow[2 * W] = decide(X2, Y2, q3, R3, L3, R2, L4, q2, q4, L2, R4, thr, thr2);
    orow[3 * W] = decide(X3, Y3, q4, R4, L4, R3, L5, q3, q5, L3, R5, thr, thr2);
    orow[4 * W] = decide(X4, Y4, q5, R5, L5, R4, L6, q4, q6, L4, R6, thr, thr2);
    orow[5 * W] = decide(X5, Y5, q6, R6, L6, R5, L7, q5, q7, L5, R7, thr, thr2);
    orow[6 * W] = decide(X6, Y6, q7, R7, L7, R6, L8, q6, q8, L6, R8, thr, thr2);
    orow[7 * W] = decide(X7, Y7, q8, R8, L8, R7, L9, q7, q9, L7, R9, thr, thr2);
  }
}

extern "C" void kernel_launch(void* const* d_in, const int* in_sizes, int n_in,
                              void* d_out, int out_size, void* d_ws, size_t ws_size,
                              hipStream_t stream) {
  const float* img = (const float*)d_in[0];
  const float* thr = (const float*)d_in[4];
  float* out = (float*)d_out;
  const int batch = in_sizes[0] / (W * H);

  dim3 grid(W / TX, H / TY, batch);
  canny_kernel<<<grid, dim3(256), 0, stream>>>(img, thr, out);
}

// Round 13
// 35.670 us; speedup vs baseline: 1.6313x; 1.2016x over previous
//
#include <hip/hip_runtime.h>
#include <math.h>

// SurrogateCanny fused kernel, round 12.
// R11 (42.9us) removed LDS staging; still VALU-bound (~33us busy / 44us wall).
// This round: (1) cheap edge-block load path -- row validity is wave-uniform
// (scalar), column-OOB only affects lanes 0/127, so guarded loads become
// clamped loads + cndmask fixups (~110 inst vs ~300); (2) nearb via
// fma(-D,bv,|c|) + min3 (7 inst vs 15; band-edge shift <=1ulp, margins have
// ~60x safety). All other phases verbatim from R11 (passed absmax 0).

constexpr int W = 1024, H = 1024;
constexpr int TX = 128, TY = 16;         // output tile per block (256 threads)
constexpr int GH = TY + 2, GSTR = 132;   // s2 plane: rows r=-1..16 (idx r+1), cols p=c+1

__device__ __forceinline__ void sobel_pair(float a00, float a01, float a02,
                                           float a10, float a12,
                                           float a20, float a21, float a22,
                                           float& gxv, float& gyv) {
  // Factored form, bit-identical to the reference row-major accumulation
  // (pow-2 scaling and negation commute with round-to-nearest; verified R8-R11).
  float t1 = 0.5f * (a02 - a00);     // == fl(-0.5*a00 + 0.5*a02)
  float t2 = t1 - a10;
  float t3 = t2 + a12;
  float t4 = t3 - 0.5f * a20;
  gxv = t4 + 0.5f * a22;
  float p1 = 0.5f * a00 + a01;       // == -fl(-0.5*a00 - a01)
  float p2 = p1 + 0.5f * a02;        // == -s2
  float u3 = 0.5f * a20 - p2;        // == fl(s2 + 0.5*a20)
  float u4 = u3 + a21;
  gyv = u4 + 0.5f * a22;
}

// Guarded global load with clamped address (never faults; 0 outside image).
// Used only by the 36-thread halo path.
__device__ __forceinline__ float gld(const float* __restrict__ im, int r, int c) {
  const bool ok = ((unsigned)r < 1024u) && ((unsigned)c < 1024u);
  const int rc = min(max(r, 0), 1023);
  const int cc = min(max(c, 0), 1023);
  const float v = im[rc * W + cc];
  return ok ? v : 0.0f;
}

// Hot path: orientation comparator network + squared-magnitude NMS with
// conservative margin, via exact max3 identity. Uncertain lanes -> exact
// reference chain, INLINE, behind a wave-uniform __any branch (as R9-R11).
__device__ __forceinline__ float decide(float gxv, float gyv, float sc,
                                        float s0a, float s0b, float s1a, float s1b,
                                        float s2a, float s2b, float s3a, float s3b,
                                        float thr, float thr2) {
#pragma clang fp contract(off)
  const float T1 = 0.19891236737965801f, D1 = 5.0e-5f;
  const float T2 = 0.66817863791929898f, D2 = 7.0e-5f;
  const float T3 = 1.49660576266548901f, D3 = 1.5e-4f;
  const float T4 = 5.02733949212584810f, D4 = 1.2e-3f;

  const float av = fabsf(gyv), bv = fabsf(gxv);
  const float c1 = fmaf(-T1, bv, av);
  const float c2 = fmaf(-T2, bv, av);
  const float c3 = fmaf(-T3, bv, av);
  const float c4 = fmaf(-T4, bv, av);

  // nearb: |c_i| < D_i*bv  <=>  fma(-D_i, bv, |c_i|) < 0 (within 1ulp of the
  // band edge; margins D_i have ~60x safety, so coverage is preserved).
  const float e1 = fmaf(-D1, bv, fabsf(c1));
  const float e2 = fmaf(-D2, bv, fabsf(c2));
  const float e3 = fmaf(-D3, bv, fabsf(c3));
  const float e4 = fmaf(-D4, bv, fabsf(c4));
  const float emin = fminf(fminf(e1, e2), fminf(e3, e4));
  const bool nearb = emin < 0.0f;

  const unsigned sgn = (__float_as_uint(gyv) ^ __float_as_uint(gxv)) >> 31;

  // per-direction max of {n1, n2, thr2}: keep_d <=> sc > m_d (exact identity)
  const float m0 = fmaxf(fmaxf(s0a, s0b), thr2);
  const float m1 = fmaxf(fmaxf(s1a, s1b), thr2);
  const float m2 = fmaxf(fmaxf(s2a, s2b), thr2);
  const float m3 = fmaxf(fmaxf(s3a, s3b), thr2);
  float m;
  if (c1 < 0.0f)      m = m0;
  else if (c2 < 0.0f) m = sgn ? m3 : m1;
  else if (c3 < 0.0f) m = m2;
  else if (c4 < 0.0f) m = sgn ? m1 : m3;
  else                m = m0;

  const float scl = sc * 0.999998f;
  const bool raw  = (sc  > m);
  const bool sure = (scl > m);

  const bool need = nearb || (raw != sure);
  float res = sure ? 1.0f : 0.0f;

  if (__builtin_expect(__any((int)need), 0)) {
    const float C = (float)(360.0 / M_PI);
    float r  = gyv / gxv;
    float t  = atanf(r);
    float u  = t * C;
    float v2 = u + 180.0f;
    float w  = v2 / 45.0f;
    int   kk = (int)rintf(w);
    int   dd = kk & 3;
    float sn1e = (dd == 0) ? s0a : (dd == 1) ? s1a : (dd == 2) ? s2a : s3a;
    float sn2e = (dd == 0) ? s0b : (dd == 1) ? s1b : (dd == 2) ? s2b : s3b;
    float gmc = sqrtf(sc), n1 = sqrtf(sn1e), n2 = sqrtf(sn2e);
    bool keep = (gmc - n1 > 0.0f) && (gmc - n2 > 0.0f) && (gmc - thr > 0.0f);
    float slow = keep ? 1.0f : 0.0f;
    res = need ? slow : res;
  }
  return res;
}

__global__ __launch_bounds__(256)
void canny_kernel(const float* __restrict__ img, const float* __restrict__ thrp,
                  float* __restrict__ out) {
#pragma clang fp contract(off)
  __shared__ __align__(16) float s_sq[GH][GSTR];   // squared grad magnitude

  const int b   = blockIdx.z;
  const int bx0 = blockIdx.x * TX;
  const int by0 = blockIdx.y * TY;
  const float* im = img + (size_t)b * (W * H);
  float* ob       = out + (size_t)b * (W * H);
  const int tid = threadIdx.x;
  const bool edge = (bx0 == 0) || (bx0 + TX == W) || (by0 == 0) || (by0 + TY == H);

  const int c  = tid & 127;           // owned column (image col bx0+c)
  const int tz = tid >> 7;            // wave-uniform strip id (0 or 1)
  const int k0 = 9 * tz;              // first s_sq row idx this thread computes

  // ---- load 11 rows x 3 cols of img directly from global ----
  // value(j,d) == img[by0 + k0 - 2 + j][bx0 + c - 1 + d], zero outside image.
  float iA0, iB0, iC0, iA1, iB1, iC1, iA2, iB2, iC2, iA3, iB3, iC3;
  float iA4, iB4, iC4, iA5, iB5, iC5, iA6, iB6, iC6, iA7, iB7, iC7;
  float iA8, iB8, iC8, iA9, iB9, iC9, iA10, iB10, iC10;
  if (!edge) {
    const float* p = im + (size_t)(by0 + k0 - 2) * W + (bx0 + c - 1);
    iA0  = p[0 * W + 0];  iB0  = p[0 * W + 1];  iC0  = p[0 * W + 2];
    iA1  = p[1 * W + 0];  iB1  = p[1 * W + 1];  iC1  = p[1 * W + 2];
    iA2  = p[2 * W + 0];  iB2  = p[2 * W + 1];  iC2  = p[2 * W + 2];
    iA3  = p[3 * W + 0];  iB3  = p[3 * W + 1];  iC3  = p[3 * W + 2];
    iA4  = p[4 * W + 0];  iB4  = p[4 * W + 1];  iC4  = p[4 * W + 2];
    iA5  = p[5 * W + 0];  iB5  = p[5 * W + 1];  iC5  = p[5 * W + 2];
    iA6  = p[6 * W + 0];  iB6  = p[6 * W + 1];  iC6  = p[6 * W + 2];
    iA7  = p[7 * W + 0];  iB7  = p[7 * W + 1];  iC7  = p[7 * W + 2];
    iA8  = p[8 * W + 0];  iB8  = p[8 * W + 1];  iC8  = p[8 * W + 2];
    iA9  = p[9 * W + 0];  iB9  = p[9 * W + 1];  iC9  = p[9 * W + 2];
    iA10 = p[10 * W + 0]; iB10 = p[10 * W + 1]; iC10 = p[10 * W + 2];
  } else {
    // Cheap edge path: row validity is WAVE-UNIFORM (scalar branch-free via
    // uniform cndmask); column OOB affects only lanes 0/127 of boundary
    // blocks -> clamp addresses once, fix values with cndmask.
    const int cb = bx0 + c;
    const int ccm1 = max(cb - 1, 0);
    const int ccp1 = min(cb + 1, 1023);
    const bool okL = (cb - 1) >= 0;
    const bool okR = (cb + 1) <= 1023;
    const int r0 = by0 + k0 - 2;
#define LOADROW(J, VA, VB, VC)                                                \
    {                                                                         \
      const int rj = r0 + (J);                                                \
      const bool rOK = (unsigned)rj < 1024u;      /* wave-uniform */          \
      const int rc = min(max(rj, 0), 1023);       /* wave-uniform */          \
      const float* rp = im + (size_t)rc * W;                                  \
      const float va = rp[ccm1], vb = rp[cb], vc = rp[ccp1];                  \
      VA = (rOK && okL) ? va : 0.0f;                                          \
      VB = rOK ? vb : 0.0f;                                                   \
      VC = (rOK && okR) ? vc : 0.0f;                                          \
    }
    LOADROW(0, iA0, iB0, iC0)
    LOADROW(1, iA1, iB1, iC1)
    LOADROW(2, iA2, iB2, iC2)
    LOADROW(3, iA3, iB3, iC3)
    LOADROW(4, iA4, iB4, iC4)
    LOADROW(5, iA5, iB5, iC5)
    LOADROW(6, iA6, iB6, iC6)
    LOADROW(7, iA7, iB7, iC7)
    LOADROW(8, iA8, iB8, iC8)
    LOADROW(9, iA9, iB9, iC9)
    LOADROW(10, iA10, iB10, iC10)
#undef LOADROW
  }

  const int rowim0 = by0 + k0 - 1;    // image row of s_sq idx k0

  float t0, t1, t2, t3, t4, t5, t6, t7, t8;
  float sx0, sx1, sx2, sx3, sx4, sx5, sx6, sx7, sx8;
  float sy0, sy1, sy2, sy3, sy4, sy5, sy6, sy7, sy8;

#define GM_ROW(J, A0, B0, C0, A1, C1, A2, B2, C2, T, SX, SY)                   \
  {                                                                            \
    float gxv, gyv;                                                            \
    sobel_pair(A0, B0, C0, A1, C1, A2, B2, C2, gxv, gyv);                      \
    float sq = gxv * gxv + gyv * gyv;                                          \
    if (edge) { if ((unsigned)(rowim0 + J) >= 1024u) sq = 0.0f; }              \
    s_sq[k0 + J][c + 1] = sq;                                                  \
    T = sq; SX = gxv; SY = gyv;                                                \
  }

  GM_ROW(0, iA0, iB0, iC0, iA1, iC1, iA2, iB2, iC2, t0, sx0, sy0)
  GM_ROW(1, iA1, iB1, iC1, iA2, iC2, iA3, iB3, iC3, t1, sx1, sy1)
  GM_ROW(2, iA2, iB2, iC2, iA3, iC3, iA4, iB4, iC4, t2, sx2, sy2)
  GM_ROW(3, iA3, iB3, iC3, iA4, iC4, iA5, iB5, iC5, t3, sx3, sy3)
  GM_ROW(4, iA4, iB4, iC4, iA5, iC5, iA6, iB6, iC6, t4, sx4, sy4)
  GM_ROW(5, iA5, iB5, iC5, iA6, iC6, iA7, iB7, iC7, t5, sx5, sy5)
  GM_ROW(6, iA6, iB6, iC6, iA7, iC7, iA8, iB8, iC8, t6, sx6, sy6)
  GM_ROW(7, iA7, iB7, iC7, iA8, iC8, iA9, iB9, iC9, t7, sx7, sy7)
  GM_ROW(8, iA8, iB8, iC8, iA9, iC9, iA10, iB10, iC10, t8, sx8, sy8)
#undef GM_ROW

  // halo cols c=-1 (p=0) and c=128 (p=129): rows r=-1..16 -> 36 elements
  if (tid < 36) {
    int rr = tid >> 1;                     // 0..17, gm row r = rr-1
    int r  = rr - 1;
    int cc = (tid & 1) ? 128 : -1;
    int hr = by0 - 2 + rr;                 // image row of window top
    int hc = bx0 + cc;                     // image col of window center
    float gxv, gyv;
    sobel_pair(gld(im, hr, hc - 1),     gld(im, hr, hc),     gld(im, hr, hc + 1),
               gld(im, hr + 1, hc - 1),                      gld(im, hr + 1, hc + 1),
               gld(im, hr + 2, hc - 1), gld(im, hr + 2, hc), gld(im, hr + 2, hc + 1),
               gxv, gyv);
    float sq = gxv * gxv + gyv * gyv;
    if (!((unsigned)(by0 + r) < 1024u && (unsigned)(bx0 + cc) < 1024u)) sq = 0.0f;
    s_sq[rr][cc + 1] = sq;
  }
  __syncthreads();

  // ---- pixel phase: 8-pixel column per thread (verbatim R11) ----
  {
    const float thr  = *thrp;
    const float thr2 = thr * thr;
    const int gb = 8 * tz;
    const float L0 = s_sq[gb + 0][c], R0 = s_sq[gb + 0][c + 2];
    const float L1 = s_sq[gb + 1][c], R1 = s_sq[gb + 1][c + 2];
    const float L2 = s_sq[gb + 2][c], R2 = s_sq[gb + 2][c + 2];
    const float L3 = s_sq[gb + 3][c], R3 = s_sq[gb + 3][c + 2];
    const float L4 = s_sq[gb + 4][c], R4 = s_sq[gb + 4][c + 2];
    const float L5 = s_sq[gb + 5][c], R5 = s_sq[gb + 5][c + 2];
    const float L6 = s_sq[gb + 6][c], R6 = s_sq[gb + 6][c + 2];
    const float L7 = s_sq[gb + 7][c], R7 = s_sq[gb + 7][c + 2];
    const float L8 = s_sq[gb + 8][c], R8 = s_sq[gb + 8][c + 2];
    const float L9 = s_sq[gb + 9][c], R9 = s_sq[gb + 9][c + 2];

    float q0, q1, q2, q3, q4, q5, q6, q7, q8, q9;
    float X0, X1, X2, X3, X4, X5, X6, X7;
    float Y0, Y1, Y2, Y3, Y4, Y5, Y6, Y7;
    if (tz == 0) {
      q0 = t0; q1 = t1; q2 = t2; q3 = t3; q4 = t4;
      q5 = t5; q6 = t6; q7 = t7; q8 = t8;
      q9 = s_sq[9][c + 1];
      X0 = sx1; X1 = sx2; X2 = sx3; X3 = sx4; X4 = sx5; X5 = sx6; X6 = sx7; X7 = sx8;
      Y0 = sy1; Y1 = sy2; Y2 = sy3; Y3 = sy4; Y4 = sy5; Y5 = sy6; Y6 = sy7; Y7 = sy8;
    } else {
      q0 = s_sq[8][c + 1];
      q1 = t0; q2 = t1; q3 = t2; q4 = t3; q5 = t4;
      q6 = t5; q7 = t6; q8 = t7; q9 = t8;
      X0 = sx0; X1 = sx1; X2 = sx2; X3 = sx3; X4 = sx4; X5 = sx5; X6 = sx6; X7 = sx7;
      Y0 = sy0; Y1 = sy1; Y2 = sy2; Y3 = sy3; Y4 = sy4; Y5 = sy5; Y6 = sy6; Y7 = sy7;
    }

    float* orow = ob + (size_t)(by0 + gb) * W + bx0 + c;

    // pixel k: sc=q[k+1]; d0:(R[k+1],L[k+1]) d1:(R[k],L[k+2])
    //          d2:(q[k],q[k+2]) d3:(L[k],R[k+2])
    orow[0 * W] = decide(X0, Y0, q1, R1, L1, R0, L2, q0, q2, L0, R2, thr, thr2);
    orow[1 * W] = decide(X1, Y1, q2, R2, L2, R1, L3, q1, q3, L1, R3, thr, thr2);
    orow[2 * W] = decide(X2, Y2, q3, R3, L3, R2, L4, q2, q4, L2, R4, thr, thr2);
    orow[3 * W] = decide(X3, Y3, q4, R4, L4, R3, L5, q3, q5, L3, R5, thr, thr2);
    orow[4 * W] = decide(X4, Y4, q5, R5, L5, R4, L6, q4, q6, L4, R6, thr, thr2);
    orow[5 * W] = decide(X5, Y5, q6, R6, L6, R5, L7, q5, q7, L5, R7, thr, thr2);
    orow[6 * W] = decide(X6, Y6, q7, R7, L7, R6, L8, q6, q8, L6, R8, thr, thr2);
    orow[7 * W] = decide(X7, Y7, q8, R8, L8, R7, L9, q7, q9, L7, R9, thr, thr2);
  }
}

extern "C" void kernel_launch(void* const* d_in, const int* in_sizes, int n_in,
                              void* d_out, int out_size, void* d_ws, size_t ws_size,
                              hipStream_t stream) {
  const float* img = (const float*)d_in[0];
  const float* thr = (const float*)d_in[4];
  float* out = (float*)d_out;
  const int batch = in_sizes[0] / (W * H);

  dim3 grid(W / TX, H / TY, batch);
  canny_kernel<<<grid, dim3(256), 0, stream>>>(img, thr, out);
}